// Round 3
// baseline (291.379 us; speedup 1.0000x reference)
//
#include <hip/hip_runtime.h>
#include <hip/hip_bf16.h>

// Problem constants: B=4, N=1024, C=768, H=12, D=64, 3C=2304, SCALE = 1/8
// Interface dtypes: inputs fp32 (reference dtype), output fp32.
// Internal math: bf16 MFMA (threshold 1.37e-2 is bf16-scale).

typedef __bf16 bf16x8 __attribute__((ext_vector_type(8)));
typedef float  f32x4  __attribute__((ext_vector_type(4)));

__device__ __forceinline__ bf16x8 cvt8(const float* p) {
    f32x4 f0 = *(const f32x4*)p;
    f32x4 f1 = *(const f32x4*)(p + 4);
    bf16x8 r;
    r[0] = (__bf16)f0[0]; r[1] = (__bf16)f0[1]; r[2] = (__bf16)f0[2]; r[3] = (__bf16)f0[3];
    r[4] = (__bf16)f1[0]; r[5] = (__bf16)f1[1]; r[6] = (__bf16)f1[2]; r[7] = (__bf16)f1[3];
    return r;
}

// ---------------------------------------------------------------------------
// QKV GEMM: out[m][n] = sum_k A[m][k] * W[n][k] + bias[n]
// A = x1 (z=0) or x2 (z=1), fp32 [4096 x 768]. W fp32 [2304 x 768].
// Epilogue scatters into q/k/v [2,B,H,N,D] bf16, q scaled by 1/8.
// ---------------------------------------------------------------------------
__global__ __launch_bounds__(256)
void gemm_qkv(const float* __restrict__ A0, const float* __restrict__ A1,
              const float* __restrict__ W,  const float* __restrict__ bias,
              __bf16* __restrict__ o0, __bf16* __restrict__ o1,
              __bf16* __restrict__ o2)
{
    constexpr int K   = 768;
    constexpr int LDA = 40;            // 32 + 8 pad
    __shared__ __bf16 As[64 * LDA];
    __shared__ __bf16 Bs[64 * LDA];

    const int t    = threadIdx.x;
    const int w    = t >> 6;
    const int lane = t & 63;
    const int l15  = lane & 15;
    const int quad = lane >> 4;
    const int gx = blockIdx.x, gy = blockIdx.y, s = blockIdx.z;

    const float* Ag = (s == 0 ? A0 : A1) + (size_t)gy * 64 * K + (t >> 2) * K + (t & 3) * 8;
    const float* Wg = W + ((size_t)gx * 64 + (t >> 2)) * K + (t & 3) * 8;
    __bf16* as_w = As + (t >> 2) * LDA + (t & 3) * 8;
    __bf16* bs_w = Bs + (t >> 2) * LDA + (t & 3) * 8;

    f32x4 acc[4];
#pragma unroll
    for (int i = 0; i < 4; i++) acc[i] = f32x4{0.f, 0.f, 0.f, 0.f};

    for (int k0 = 0; k0 < K; k0 += 32) {
        *(bf16x8*)as_w = cvt8(Ag + k0);
        *(bf16x8*)bs_w = cvt8(Wg + k0);
        __syncthreads();
        bf16x8 a = *(const bf16x8*)(As + (w * 16 + l15) * LDA + quad * 8);
#pragma unroll
        for (int ns = 0; ns < 4; ns++) {
            bf16x8 b = *(const bf16x8*)(Bs + (ns * 16 + l15) * LDA + quad * 8);
            acc[ns] = __builtin_amdgcn_mfma_f32_16x16x32_bf16(a, b, acc[ns], 0, 0, 0);
        }
        __syncthreads();
    }

    // col j in [0,2304): which = j/768 (q/k/v), c = j%768, h = c/64, d = c%64
#pragma unroll
    for (int ns = 0; ns < 4; ns++) {
        int j     = gx * 64 + ns * 16 + l15;
        int which = j / 768;
        int c     = j - which * 768;
        int h = c >> 6, d = c & 63;
        float bj  = bias[j];
        __bf16* dst = (which == 0) ? o0 : (which == 1 ? o1 : o2);
        float scl   = (which == 0) ? 0.125f : 1.f;
#pragma unroll
        for (int r = 0; r < 4; r++) {
            int row = gy * 64 + w * 16 + quad * 4 + r;   // 0..4095 in stream
            int b = row >> 10, tok = row & 1023;
            size_t idx = (((size_t)((s * 4 + b) * 12 + h) * 1024 + tok) * 64 + d);
            dst[idx] = (__bf16)((acc[ns][r] + bj) * scl);
        }
    }
}

// ---------------------------------------------------------------------------
// Proj GEMM: A = o_ws bf16 [8192 x 768], W fp32 [768 x 768], out fp32 d_out.
// ---------------------------------------------------------------------------
__global__ __launch_bounds__(256)
void gemm_proj(const __bf16* __restrict__ A, const float* __restrict__ W,
               const float* __restrict__ bias, float* __restrict__ out)
{
    constexpr int K   = 768;
    constexpr int LDA = 40;
    __shared__ __bf16 As[64 * LDA];
    __shared__ __bf16 Bs[64 * LDA];

    const int t    = threadIdx.x;
    const int w    = t >> 6;
    const int lane = t & 63;
    const int l15  = lane & 15;
    const int quad = lane >> 4;
    const int gx = blockIdx.x, gy = blockIdx.y;

    const __bf16* Ag = A + (size_t)gy * 64 * K + (t >> 2) * K + (t & 3) * 8;
    const float*  Wg = W + ((size_t)gx * 64 + (t >> 2)) * K + (t & 3) * 8;
    __bf16* as_w = As + (t >> 2) * LDA + (t & 3) * 8;
    __bf16* bs_w = Bs + (t >> 2) * LDA + (t & 3) * 8;

    f32x4 acc[4];
#pragma unroll
    for (int i = 0; i < 4; i++) acc[i] = f32x4{0.f, 0.f, 0.f, 0.f};

    for (int k0 = 0; k0 < K; k0 += 32) {
        *(bf16x8*)as_w = *(const bf16x8*)(Ag + k0);
        *(bf16x8*)bs_w = cvt8(Wg + k0);
        __syncthreads();
        bf16x8 a = *(const bf16x8*)(As + (w * 16 + l15) * LDA + quad * 8);
#pragma unroll
        for (int ns = 0; ns < 4; ns++) {
            bf16x8 b = *(const bf16x8*)(Bs + (ns * 16 + l15) * LDA + quad * 8);
            acc[ns] = __builtin_amdgcn_mfma_f32_16x16x32_bf16(a, b, acc[ns], 0, 0, 0);
        }
        __syncthreads();
    }

#pragma unroll
    for (int ns = 0; ns < 4; ns++) {
        int col  = gx * 64 + ns * 16 + l15;
        float bj = bias[col];
#pragma unroll
        for (int r = 0; r < 4; r++) {
            int row = gy * 64 + w * 16 + quad * 4 + r;   // 0..8191
            out[(size_t)row * 768 + col] = acc[ns][r] + bj;
        }
    }
}

// ---------------------------------------------------------------------------
// Dual-stream flash attention.  Grid: (16 q-tiles, 48 b*h).  Block: 256 = 4 waves.
// Each wave owns 16 query rows.  S = q1s@k1^T + q2s@k2^T (scale folded into q),
// online softmax over 16 key-tiles of 64, then O_s += P @ V_s for both streams.
// ---------------------------------------------------------------------------
__global__ __launch_bounds__(256)
void attn_k(const __bf16* __restrict__ qws, const __bf16* __restrict__ kws,
            const __bf16* __restrict__ vws, __bf16* __restrict__ ows)
{
    constexpr int LDK = 72;            // 64 + 8 pad
    __shared__ __bf16 Qs[2][64 * LDK];
    __shared__ __bf16 Ks[2][64 * LDK];
    __shared__ __bf16 Vt[2][64 * LDK]; // V transposed: [d][key]
    __shared__ __bf16 Ps[64 * LDK];

    const int qt = blockIdx.x;         // 0..15
    const int bh = blockIdx.y;         // 0..47
    const int b = bh / 12, h = bh % 12;
    const int t    = threadIdx.x;
    const int w    = t >> 6;
    const int lane = t & 63;
    const int l15  = lane & 15;
    const int quad = lane >> 4;

    const size_t head_off      = ((size_t)(b * 12 + h)) * 1024 * 64;
    const size_t stream_stride = (size_t)4 * 12 * 1024 * 64;

    // Stage Q tiles once: 64 rows x 64 dims per stream
    {
        const int row = t >> 2, c0 = (t & 3) * 16;
#pragma unroll
        for (int s = 0; s < 2; s++) {
            const __bf16* qp = qws + s * stream_stride + head_off + (size_t)(qt * 64) * 64;
            *(bf16x8*)(&Qs[s][row * LDK + c0])     = *(const bf16x8*)(qp + row * 64 + c0);
            *(bf16x8*)(&Qs[s][row * LDK + c0 + 8]) = *(const bf16x8*)(qp + row * 64 + c0 + 8);
        }
    }

    float m_prev[4] = {-1e30f, -1e30f, -1e30f, -1e30f};
    float l_run[4]  = {0.f, 0.f, 0.f, 0.f};
    f32x4 accO[2][4];
#pragma unroll
    for (int s = 0; s < 2; s++)
#pragma unroll
        for (int ns = 0; ns < 4; ns++) accO[s][ns] = f32x4{0.f, 0.f, 0.f, 0.f};

    for (int kt = 0; kt < 16; kt++) {
        __syncthreads();   // previous iteration's reads done before restage
        {
            const int row = t >> 2, c0 = (t & 3) * 16;
#pragma unroll
            for (int s = 0; s < 2; s++) {
                const __bf16* kp = kws + s * stream_stride + head_off + (size_t)(kt * 64) * 64;
                *(bf16x8*)(&Ks[s][row * LDK + c0])     = *(const bf16x8*)(kp + row * 64 + c0);
                *(bf16x8*)(&Ks[s][row * LDK + c0 + 8]) = *(const bf16x8*)(kp + row * 64 + c0 + 8);
                // V transposed: key = t&63, 16 d's per thread
                const __bf16* vp = vws + s * stream_stride + head_off + (size_t)(kt * 64) * 64;
                int key = t & 63, dg = t >> 6;
                bf16x8 v0 = *(const bf16x8*)(vp + key * 64 + dg * 16);
                bf16x8 v1 = *(const bf16x8*)(vp + key * 64 + dg * 16 + 8);
#pragma unroll
                for (int i = 0; i < 8; i++) {
                    Vt[s][(dg * 16 + i) * LDK + key]     = v0[i];
                    Vt[s][(dg * 16 + 8 + i) * LDK + key] = v1[i];
                }
            }
        }
        __syncthreads();

        // S tile: 16 q-rows (this wave) x 64 keys, summed over both streams
        f32x4 accS[4];
#pragma unroll
        for (int i = 0; i < 4; i++) accS[i] = f32x4{0.f, 0.f, 0.f, 0.f};
#pragma unroll
        for (int s = 0; s < 2; s++)
#pragma unroll
            for (int kk = 0; kk < 2; kk++) {
                bf16x8 a = *(const bf16x8*)(&Qs[s][(w * 16 + l15) * LDK + kk * 32 + quad * 8]);
#pragma unroll
                for (int ns = 0; ns < 4; ns++) {
                    bf16x8 bf = *(const bf16x8*)(&Ks[s][(ns * 16 + l15) * LDK + kk * 32 + quad * 8]);
                    accS[ns] = __builtin_amdgcn_mfma_f32_16x16x32_bf16(a, bf, accS[ns], 0, 0, 0);
                }
            }

        // Online softmax: row (w*16 + quad*4 + r); 64 cols live in l15 x ns
        float p[4][4];
#pragma unroll
        for (int r = 0; r < 4; r++) {
            float mx = fmaxf(fmaxf(accS[0][r], accS[1][r]), fmaxf(accS[2][r], accS[3][r]));
#pragma unroll
            for (int off = 1; off < 16; off <<= 1) mx = fmaxf(mx, __shfl_xor(mx, off));
            float mnew  = fmaxf(m_prev[r], mx);
            float alpha = __expf(m_prev[r] - mnew);
            float rs = 0.f;
#pragma unroll
            for (int ns = 0; ns < 4; ns++) {
                float pv = __expf(accS[ns][r] - mnew);
                p[ns][r] = pv;
                rs += pv;
            }
#pragma unroll
            for (int off = 1; off < 16; off <<= 1) rs += __shfl_xor(rs, off);
            l_run[r]  = l_run[r] * alpha + rs;
            m_prev[r] = mnew;
#pragma unroll
            for (int s = 0; s < 2; s++)
#pragma unroll
                for (int ns = 0; ns < 4; ns++) accO[s][ns][r] *= alpha;
        }

        // P: C-layout regs -> LDS (A-layout readable). Wave owns its 16 rows.
#pragma unroll
        for (int ns = 0; ns < 4; ns++)
#pragma unroll
            for (int r = 0; r < 4; r++)
                Ps[(w * 16 + quad * 4 + r) * LDK + ns * 16 + l15] = (__bf16)p[ns][r];
        __syncthreads();

        // O_s += P @ V_s   (B-operand from transposed V: contiguous keys)
#pragma unroll
        for (int kk = 0; kk < 2; kk++) {
            bf16x8 a = *(const bf16x8*)(&Ps[(w * 16 + l15) * LDK + kk * 32 + quad * 8]);
#pragma unroll
            for (int s = 0; s < 2; s++)
#pragma unroll
                for (int ns = 0; ns < 4; ns++) {
                    bf16x8 bf = *(const bf16x8*)(&Vt[s][(ns * 16 + l15) * LDK + kk * 32 + quad * 8]);
                    accO[s][ns] = __builtin_amdgcn_mfma_f32_16x16x32_bf16(a, bf, accO[s][ns], 0, 0, 0);
                }
        }
    }

    // Epilogue: o[s] row = token, col = h*64 + d; layout [2,B,N,C]
#pragma unroll
    for (int r = 0; r < 4; r++) {
        float inv = 1.f / l_run[r];
        int tok = qt * 64 + w * 16 + quad * 4 + r;
#pragma unroll
        for (int s = 0; s < 2; s++)
#pragma unroll
            for (int ns = 0; ns < 4; ns++) {
                size_t idx = ((size_t)((s * 4 + b) * 1024 + tok)) * 768 + h * 64 + ns * 16 + l15;
                ows[idx] = (__bf16)(accO[s][ns][r] * inv);
            }
    }
}

// ---------------------------------------------------------------------------
extern "C" void kernel_launch(void* const* d_in, const int* in_sizes, int n_in,
                              void* d_out, int out_size, void* d_ws, size_t ws_size,
                              hipStream_t stream)
{
    const float* x1    = (const float*)d_in[0];
    const float* x2    = (const float*)d_in[1];
    const float* Wqkv  = (const float*)d_in[2];
    const float* bqkv  = (const float*)d_in[3];
    const float* Wproj = (const float*)d_in[4];
    const float* bproj = (const float*)d_in[5];
    float* out = (float*)d_out;

    // ws layout (bf16 elems): q[2,B,H,N,D] | k | v | o[2,B,N,C]  (~50 MB)
    const size_t qkv_elems = (size_t)2 * 4 * 12 * 1024 * 64;   // 6,291,456
    __bf16* q_ws = (__bf16*)d_ws;
    __bf16* k_ws = q_ws + qkv_elems;
    __bf16* v_ws = k_ws + qkv_elems;
    __bf16* o_ws = v_ws + qkv_elems;

    // 1) QKV GEMM: [4096 x 768] @ [2304 x 768]^T per stream (fp32 in, bf16 out)
    gemm_qkv<<<dim3(36, 64, 2), 256, 0, stream>>>(x1, x2, Wqkv, bqkv,
                                                  q_ws, k_ws, v_ws);
    // 2) dual-stream flash attention (bf16)
    attn_k<<<dim3(16, 48), 256, 0, stream>>>(q_ws, k_ws, v_ws, o_ws);
    // 3) proj GEMM: [8192 x 768] @ [768 x 768]^T -> d_out fp32 (y1 ‖ y2)
    gemm_proj<<<dim3(12, 128), 256, 0, stream>>>(o_ws, Wproj, bproj, out);
}

// Round 4
// 268.119 us; speedup vs baseline: 1.0868x; 1.0868x over previous
//
#include <hip/hip_runtime.h>
#include <hip/hip_bf16.h>

// B=4, N=1024, C=768, H=12, D=64, SCALE=1/8. Inputs fp32, output fp32.
// Internal math bf16 MFMA. fp32->bf16 pre-convert enables global_load_lds(16B).

typedef __bf16 bf16x8 __attribute__((ext_vector_type(8)));
typedef float  f32x4  __attribute__((ext_vector_type(4)));

__device__ __forceinline__ bf16x8 cvt8(const float* p) {
    f32x4 f0 = *(const f32x4*)p;
    f32x4 f1 = *(const f32x4*)(p + 4);
    bf16x8 r;
    r[0] = (__bf16)f0[0]; r[1] = (__bf16)f0[1]; r[2] = (__bf16)f0[2]; r[3] = (__bf16)f0[3];
    r[4] = (__bf16)f1[0]; r[5] = (__bf16)f1[1]; r[6] = (__bf16)f1[2]; r[7] = (__bf16)f1[3];
    return r;
}

__device__ __forceinline__ void async16(const __bf16* g, __bf16* l) {
    __builtin_amdgcn_global_load_lds(
        (const __attribute__((address_space(1))) void*)g,
        (__attribute__((address_space(3))) void*)l, 16, 0, 0);
}

// ---------------------------------------------------------------------------
// fp32 -> bf16 convert, 8 elems/thread (all sizes divide 2048)
// ---------------------------------------------------------------------------
__global__ __launch_bounds__(256)
void cvt_k(const float* __restrict__ src, __bf16* __restrict__ dst, int n) {
    int i = (blockIdx.x * 256 + threadIdx.x) * 8;
    if (i < n) *(bf16x8*)(dst + i) = cvt8(src + i);
}

// ---------------------------------------------------------------------------
// 128x128-tile QKV GEMM, one stream per launch (A = converted x, 4096x768).
// W bf16 [2304 x 768]. Scatter: q,k -> [2,B,H,N,D] (q * 1/8), v -> [2,B,H,D,N].
// m97 structure: global_load_lds(16), BK=32, no-pad LDS, 4 waves x (4x4) acc.
// ---------------------------------------------------------------------------
__global__ __launch_bounds__(256)
void gemm_qkv_s(const __bf16* __restrict__ A, const __bf16* __restrict__ Wq,
                const float* __restrict__ bias,
                __bf16* __restrict__ qo, __bf16* __restrict__ ko,
                __bf16* __restrict__ vo, int st)
{
    constexpr int K = 768;
    __shared__ __bf16 As[128 * 32];
    __shared__ __bf16 Bs[128 * 32];

    const int t = threadIdx.x, w = t >> 6, lane = t & 63;
    const int l15 = lane & 15, quad = lane >> 4;
    const int wm = w >> 1, wn = w & 1;
    const int gx = blockIdx.x, gy = blockIdx.y;
    const int lrow = lane >> 2, lcol = (lane & 3) * 8;

    const __bf16* Ab = A  + (size_t)(gy * 128) * K;
    const __bf16* Bb = Wq + (size_t)(gx * 128) * K;

    f32x4 acc[4][4];
#pragma unroll
    for (int mi = 0; mi < 4; mi++)
#pragma unroll
        for (int ni = 0; ni < 4; ni++) acc[mi][ni] = f32x4{0.f, 0.f, 0.f, 0.f};

    for (int k0 = 0; k0 < K; k0 += 32) {
#pragma unroll
        for (int i = 0; i < 2; i++) {
            int r = w * 32 + i * 16 + lrow;
            async16(Ab + (size_t)r * K + k0 + lcol, &As[r * 32 + lcol]);
            async16(Bb + (size_t)r * K + k0 + lcol, &Bs[r * 32 + lcol]);
        }
        __syncthreads();
        bf16x8 af[4], bfr[4];
#pragma unroll
        for (int mi = 0; mi < 4; mi++)
            af[mi] = *(const bf16x8*)&As[(wm * 64 + mi * 16 + l15) * 32 + quad * 8];
#pragma unroll
        for (int ni = 0; ni < 4; ni++)
            bfr[ni] = *(const bf16x8*)&Bs[(wn * 64 + ni * 16 + l15) * 32 + quad * 8];
#pragma unroll
        for (int mi = 0; mi < 4; mi++)
#pragma unroll
            for (int ni = 0; ni < 4; ni++)
                acc[mi][ni] = __builtin_amdgcn_mfma_f32_16x16x32_bf16(af[mi], bfr[ni], acc[mi][ni], 0, 0, 0);
        __syncthreads();
    }

#pragma unroll
    for (int ni = 0; ni < 4; ni++) {
        int j     = gx * 128 + wn * 64 + ni * 16 + l15;   // 0..2303
        int which = j / 768;                               // uniform per 16-col group
        int c     = j - which * 768;
        int h = c >> 6, d = c & 63;
        float bj  = bias[j];
#pragma unroll
        for (int mi = 0; mi < 4; mi++) {
#pragma unroll
            for (int r = 0; r < 4; r++) {
                int row = gy * 128 + wm * 64 + mi * 16 + quad * 4 + r;  // 0..4095
                int b = row >> 10, tok = row & 1023;
                float val = acc[mi][ni][r] + bj;
                if (which == 0)
                    qo[((size_t)((st * 4 + b) * 12 + h) * 1024 + tok) * 64 + d] = (__bf16)(val * 0.125f);
                else if (which == 1)
                    ko[((size_t)((st * 4 + b) * 12 + h) * 1024 + tok) * 64 + d] = (__bf16)val;
                else
                    vo[((size_t)((st * 4 + b) * 12 + h) * 64 + d) * 1024 + tok] = (__bf16)val;
            }
        }
    }
}

// ---------------------------------------------------------------------------
// 128x128-tile proj GEMM: A bf16 [8192x768], W bf16 [768x768], out fp32 + bias
// ---------------------------------------------------------------------------
__global__ __launch_bounds__(256)
void gemm_proj(const __bf16* __restrict__ A, const __bf16* __restrict__ Wp,
               const float* __restrict__ bias, float* __restrict__ out)
{
    constexpr int K = 768;
    __shared__ __bf16 As[128 * 32];
    __shared__ __bf16 Bs[128 * 32];

    const int t = threadIdx.x, w = t >> 6, lane = t & 63;
    const int l15 = lane & 15, quad = lane >> 4;
    const int wm = w >> 1, wn = w & 1;
    const int gx = blockIdx.x, gy = blockIdx.y;
    const int lrow = lane >> 2, lcol = (lane & 3) * 8;

    const __bf16* Ab = A  + (size_t)(gy * 128) * K;
    const __bf16* Bb = Wp + (size_t)(gx * 128) * K;

    f32x4 acc[4][4];
#pragma unroll
    for (int mi = 0; mi < 4; mi++)
#pragma unroll
        for (int ni = 0; ni < 4; ni++) acc[mi][ni] = f32x4{0.f, 0.f, 0.f, 0.f};

    for (int k0 = 0; k0 < K; k0 += 32) {
#pragma unroll
        for (int i = 0; i < 2; i++) {
            int r = w * 32 + i * 16 + lrow;
            async16(Ab + (size_t)r * K + k0 + lcol, &As[r * 32 + lcol]);
            async16(Bb + (size_t)r * K + k0 + lcol, &Bs[r * 32 + lcol]);
        }
        __syncthreads();
        bf16x8 af[4], bfr[4];
#pragma unroll
        for (int mi = 0; mi < 4; mi++)
            af[mi] = *(const bf16x8*)&As[(wm * 64 + mi * 16 + l15) * 32 + quad * 8];
#pragma unroll
        for (int ni = 0; ni < 4; ni++)
            bfr[ni] = *(const bf16x8*)&Bs[(wn * 64 + ni * 16 + l15) * 32 + quad * 8];
#pragma unroll
        for (int mi = 0; mi < 4; mi++)
#pragma unroll
            for (int ni = 0; ni < 4; ni++)
                acc[mi][ni] = __builtin_amdgcn_mfma_f32_16x16x32_bf16(af[mi], bfr[ni], acc[mi][ni], 0, 0, 0);
        __syncthreads();
    }

#pragma unroll
    for (int ni = 0; ni < 4; ni++) {
        int col  = gx * 128 + wn * 64 + ni * 16 + l15;
        float bj = bias[col];
#pragma unroll
        for (int mi = 0; mi < 4; mi++)
#pragma unroll
            for (int r = 0; r < 4; r++) {
                int row = gy * 128 + wm * 64 + mi * 16 + quad * 4 + r;  // 0..8191
                out[(size_t)row * 768 + col] = acc[mi][ni][r] + bj;
            }
    }
}

// ---------------------------------------------------------------------------
// Dual-stream flash attention. Grid (16 q-tiles, 48 b*h), 256 thr = 4 waves.
// Q frags live in registers (wave only reads its own 16 rows). K: [.,N,D].
// V pre-transposed in global: [.,D,N] -> vectorized Vt staging.
// LDS = Ks(2) + Vt(2) + Ps = 45 KB -> 3 blocks/CU, grid = 1 residency wave.
// ---------------------------------------------------------------------------
__global__ __launch_bounds__(256)
void attn_k(const __bf16* __restrict__ qws, const __bf16* __restrict__ kws,
            const __bf16* __restrict__ vws, __bf16* __restrict__ ows)
{
    constexpr int LDK = 72;            // 64 + 8 pad
    __shared__ __bf16 Ks[2][64 * LDK];
    __shared__ __bf16 Vt[2][64 * LDK]; // [d][key]
    __shared__ __bf16 Ps[64 * LDK];

    const int qt = blockIdx.x;         // 0..15
    const int bh = blockIdx.y;         // 0..47
    const int b = bh / 12, h = bh % 12;
    const int t = threadIdx.x, w = t >> 6, lane = t & 63;
    const int l15 = lane & 15, quad = lane >> 4;

    const size_t head_off      = (size_t)(b * 12 + h) * 65536;  // 1024*64 == 64*1024
    const size_t stream_stride = (size_t)4 * 12 * 65536;

    // Q fragments in registers: wave w owns q-rows qt*64 + w*16 + l15
    bf16x8 qf[2][2];
#pragma unroll
    for (int s = 0; s < 2; s++)
#pragma unroll
        for (int kk = 0; kk < 2; kk++)
            qf[s][kk] = *(const bf16x8*)(qws + s * stream_stride + head_off
                          + (size_t)(qt * 64 + w * 16 + l15) * 64 + kk * 32 + quad * 8);

    float m_prev[4] = {-1e30f, -1e30f, -1e30f, -1e30f};
    float l_run[4]  = {0.f, 0.f, 0.f, 0.f};
    f32x4 accO[2][4];
#pragma unroll
    for (int s = 0; s < 2; s++)
#pragma unroll
        for (int ns = 0; ns < 4; ns++) accO[s][ns] = f32x4{0.f, 0.f, 0.f, 0.f};

    const int row = t >> 2, c0 = (t & 3) * 16;

    for (int kt = 0; kt < 16; kt++) {
        __syncthreads();   // prev PV reads done before restage
#pragma unroll
        for (int s = 0; s < 2; s++) {
            const __bf16* kp = kws + s * stream_stride + head_off + (size_t)(kt * 64) * 64;
            *(bf16x8*)(&Ks[s][row * LDK + c0])     = *(const bf16x8*)(kp + row * 64 + c0);
            *(bf16x8*)(&Ks[s][row * LDK + c0 + 8]) = *(const bf16x8*)(kp + row * 64 + c0 + 8);
            const __bf16* vp = vws + s * stream_stride + head_off;   // [d][key]
            *(bf16x8*)(&Vt[s][row * LDK + c0])     = *(const bf16x8*)(vp + row * 1024 + kt * 64 + c0);
            *(bf16x8*)(&Vt[s][row * LDK + c0 + 8]) = *(const bf16x8*)(vp + row * 1024 + kt * 64 + c0 + 8);
        }
        __syncthreads();

        // S tile: 16 q-rows x 64 keys, summed over both streams
        f32x4 accS[4];
#pragma unroll
        for (int i = 0; i < 4; i++) accS[i] = f32x4{0.f, 0.f, 0.f, 0.f};
#pragma unroll
        for (int s = 0; s < 2; s++)
#pragma unroll
            for (int kk = 0; kk < 2; kk++)
#pragma unroll
                for (int ns = 0; ns < 4; ns++) {
                    bf16x8 bfr = *(const bf16x8*)(&Ks[s][(ns * 16 + l15) * LDK + kk * 32 + quad * 8]);
                    accS[ns] = __builtin_amdgcn_mfma_f32_16x16x32_bf16(qf[s][kk], bfr, accS[ns], 0, 0, 0);
                }

        // Online softmax per row (w*16 + quad*4 + r)
        float p[4][4];
#pragma unroll
        for (int r = 0; r < 4; r++) {
            float mx = fmaxf(fmaxf(accS[0][r], accS[1][r]), fmaxf(accS[2][r], accS[3][r]));
#pragma unroll
            for (int off = 1; off < 16; off <<= 1) mx = fmaxf(mx, __shfl_xor(mx, off));
            float mnew  = fmaxf(m_prev[r], mx);
            float alpha = __expf(m_prev[r] - mnew);
            float rs = 0.f;
#pragma unroll
            for (int ns = 0; ns < 4; ns++) {
                float pv = __expf(accS[ns][r] - mnew);
                p[ns][r] = pv;
                rs += pv;
            }
#pragma unroll
            for (int off = 1; off < 16; off <<= 1) rs += __shfl_xor(rs, off);
            l_run[r]  = l_run[r] * alpha + rs;
            m_prev[r] = mnew;
#pragma unroll
            for (int s = 0; s < 2; s++)
#pragma unroll
                for (int ns = 0; ns < 4; ns++) accO[s][ns][r] *= alpha;
        }

        // P: C-layout -> A-layout via LDS. Intra-wave only: no barrier needed.
#pragma unroll
        for (int ns = 0; ns < 4; ns++)
#pragma unroll
            for (int r = 0; r < 4; r++)
                Ps[(w * 16 + quad * 4 + r) * LDK + ns * 16 + l15] = (__bf16)p[ns][r];

        // O_s += P @ V_s
#pragma unroll
        for (int kk = 0; kk < 2; kk++) {
            bf16x8 a = *(const bf16x8*)(&Ps[(w * 16 + l15) * LDK + kk * 32 + quad * 8]);
#pragma unroll
            for (int s = 0; s < 2; s++)
#pragma unroll
                for (int ns = 0; ns < 4; ns++) {
                    bf16x8 bfr = *(const bf16x8*)(&Vt[s][(ns * 16 + l15) * LDK + kk * 32 + quad * 8]);
                    accO[s][ns] = __builtin_amdgcn_mfma_f32_16x16x32_bf16(a, bfr, accO[s][ns], 0, 0, 0);
                }
        }
    }

    // Epilogue: o rows (s*4096 + b*1024 + tok), cols h*64 + d  -> [8192 x 768]
#pragma unroll
    for (int r = 0; r < 4; r++) {
        float inv = 1.f / l_run[r];
        int tok = qt * 64 + w * 16 + quad * 4 + r;
#pragma unroll
        for (int s = 0; s < 2; s++)
#pragma unroll
            for (int ns = 0; ns < 4; ns++) {
                size_t idx = ((size_t)((s * 4 + b) * 1024 + tok)) * 768 + h * 64 + ns * 16 + l15;
                ows[idx] = (__bf16)(accO[s][ns][r] * inv);
            }
    }
}

// ---------------------------------------------------------------------------
extern "C" void kernel_launch(void* const* d_in, const int* in_sizes, int n_in,
                              void* d_out, int out_size, void* d_ws, size_t ws_size,
                              hipStream_t stream)
{
    const float* x1    = (const float*)d_in[0];
    const float* x2    = (const float*)d_in[1];
    const float* Wqkv  = (const float*)d_in[2];
    const float* bqkv  = (const float*)d_in[3];
    const float* Wproj = (const float*)d_in[4];
    const float* bproj = (const float*)d_in[5];
    float* out = (float*)d_out;

    // ws: q | k | v | P   (4 x 6291456 bf16 = 50.33 MB, proven footprint)
    // P region multiplexed: phase A/B: Xc (3.1M) + Wqc (1.77M); phase C/D: o_ws.
    // Wpc converted into q region (dead after attn) right before proj.
    const size_t qkv_elems = (size_t)2 * 4 * 12 * 1024 * 64;   // 6,291,456
    __bf16* q_ws = (__bf16*)d_ws;
    __bf16* k_ws = q_ws + qkv_elems;
    __bf16* v_ws = k_ws + qkv_elems;
    __bf16* pool = v_ws + qkv_elems;
    __bf16* Xc  = pool;                 // 4096*768 = 3,145,728
    __bf16* Wqc = pool + 3145728;       // 2304*768 = 1,769,472
    __bf16* o_ws = pool;                // 8192*768 = 6,291,456 (after B)
    __bf16* Wpc = q_ws;                 // 768*768  =   589,824 (after attn)

    // stream 0
    cvt_k<<<1536, 256, 0, stream>>>(x1, Xc, 3145728);
    cvt_k<<<864,  256, 0, stream>>>(Wqkv, Wqc, 1769472);
    gemm_qkv_s<<<dim3(18, 32), 256, 0, stream>>>(Xc, Wqc, bqkv, q_ws, k_ws, v_ws, 0);
    // stream 1 (Xc reused)
    cvt_k<<<1536, 256, 0, stream>>>(x2, Xc, 3145728);
    gemm_qkv_s<<<dim3(18, 32), 256, 0, stream>>>(Xc, Wqc, bqkv, q_ws, k_ws, v_ws, 1);
    // attention
    attn_k<<<dim3(16, 48), 256, 0, stream>>>(q_ws, k_ws, v_ws, o_ws);
    // proj
    cvt_k<<<288, 256, 0, stream>>>(Wproj, Wpc, 589824);
    gemm_proj<<<dim3(6, 64), 256, 0, stream>>>(o_ws, Wpc, bproj, out);
}